// Round 10
// baseline (480.216 us; speedup 1.0000x reference)
//
#include <hip/hip_runtime.h>
#include <math.h>

// ---------------------------------------------------------------------------
// Moondream3Attention on MI355X (gfx950)
// T=2048, DIM=2048, H=32, HD=64, ROT=32, QKV_DIM=6144
// Pipeline (all-bf16 matmul datapath):
//   0) cvt3: hidden->hb, Wqkv->wqb, Wout->wob (fp32->bf16, one launch)
//   1) qkv split-K=2, XCD-affine: each XCD owns a 6-tile N-slice (B slice
//      ~1.5MB hot in its L2); K-halves temporally separated
//   2) tok = gelu(P0+P1) @ [tau_wq;tau_wv]^T   (split-K + atomics)
//   3) qkv_process (ushort8-vectorized): P0+P1 sum, tau gating + RoPE
//   4) attn_fa: s-split MAX-FREE flash attention, 64-q-row chunks (1 m-frag
//      per wave -> ~80 VGPR -> 6 blocks/CU), XCD-affine (4 heads/XCD)
//   5) attn_merge: O = sum_c O~_c / sum_c l_c -> attnb bf16
//   6) out = attnb @ wob^T + bout   (64x64 tile, XCD-affine, f32 out)
// Workspace (94,371,840 B), liveness-overlapped:
//   P0    bf16 [2048][6144] @ 0          (25165824)  \ dead after qkv_process,
//   P1    bf16 [2048][6144] @ 25165824   (25165824)  / reused as Opart (33.5MB)
//   wqb   bf16 [6144][2048] @ 50331648   (25165824), dead after GEMM1 ->
//     qh  bf16 [32][2048][64] @ 50331648, kh @ 58720256, vtb @ 67108864
//   hb    bf16 [2048][2048] @ 75497472   (8388608), dead after GEMM1 ->
//     tok_raw f32 [2048][64] @ 75497472 (dead after qkv_process) ->
//     attnb   bf16 [2048][2048] @ 75497472
//   ml    f32 [4096][64]    @ 83886080  (1048576)
//   wob   bf16 [2048][2048] @ 85983232  (8388608)   -> end 94371840
// ---------------------------------------------------------------------------

typedef __bf16 bf16x8 __attribute__((ext_vector_type(8)));
typedef float floatx4 __attribute__((ext_vector_type(4)));
typedef unsigned short ushort8v __attribute__((ext_vector_type(8)));

__device__ __forceinline__ unsigned short f2b(float x) {
    unsigned int b = __float_as_uint(x);
    b = b + 0x7FFFu + ((b >> 16) & 1u);   // round-to-nearest-even
    return (unsigned short)(b >> 16);
}
__device__ __forceinline__ unsigned short f2b_trunc(float x) {
    return (unsigned short)(__float_as_uint(x) >> 16);   // cheap, for P only
}
__device__ __forceinline__ float b2f(unsigned short u) {
    return __uint_as_float(((unsigned int)u) << 16);
}
__device__ __forceinline__ float gelu_f(float x) {
    return 0.5f * x * (1.0f + erff(x * 0.70710678118654752440f));
}
__device__ __forceinline__ float fexp2(float x) {
    return __builtin_amdgcn_exp2f(x);     // raw v_exp_f32; x=-1e30 -> 0
}
__device__ __forceinline__ floatx4 mfma16(bf16x8 a, bf16x8 b, floatx4 c) {
    return __builtin_amdgcn_mfma_f32_16x16x32_bf16(a, b, c, 0, 0, 0);
}
// async global->LDS, 16B per lane; lane i lands at ldsbase + i*16
__device__ __forceinline__ void gl2lds16(const unsigned short* g, unsigned short* l) {
    __builtin_amdgcn_global_load_lds(
        (__attribute__((address_space(1))) void*)g,
        (__attribute__((address_space(3))) void*)l, 16, 0, 0);
}

// inv_freq[i] = 1e6^(-i/16), i = 0..15
__constant__ float INV_FREQ[16] = {
    1.0f, 0.42169650342858224f, 0.17782794100389228f, 0.074989420933245582f,
    0.031622776601683791f, 0.013335214321633240f, 0.0056234132519034908f,
    0.0023713737056616552f, 0.001f, 4.2169650342858224e-4f,
    1.7782794100389228e-4f, 7.4989420933245582e-5f, 3.1622776601683791e-5f,
    1.3335214321633240e-5f, 5.6234132519034908e-6f, 2.3713737056616552e-6f
};

// s-chunk schedule, 64-q-row tiles (qt in [0,32)): nc = qt/8+1 chunks of 512 s.
// 80 chunks/head, longest-first: 48 fulls (8 steps), then finals by length.
__constant__ unsigned char CHUNK_QT[80] = {
    31,31,31, 30,30,30, 29,29,29, 28,28,28, 27,27,27, 26,26,26, 25,25,25, 24,24,24,
    23,23, 22,22, 21,21, 20,20, 19,19, 18,18, 17,17, 16,16,
    15,14,13,12,11,10,9,8,
    31,23,15,7, 30,22,14,6, 29,21,13,5, 28,20,12,4,
    27,19,11,3, 26,18,10,2, 25,17,9,1, 24,16,8,0};
__constant__ unsigned char CHUNK_C[80] = {
    0,1,2, 0,1,2, 0,1,2, 0,1,2, 0,1,2, 0,1,2, 0,1,2, 0,1,2,
    0,1, 0,1, 0,1, 0,1, 0,1, 0,1, 0,1, 0,1,
    0,0,0,0,0,0,0,0,
    3,2,1,0, 3,2,1,0, 3,2,1,0, 3,2,1,0,
    3,2,1,0, 3,2,1,0, 3,2,1,0, 3,2,1,0};

// ---------------------------------------------------------------------------
// One-launch fp32->bf16 conversion of three buffers.
// ---------------------------------------------------------------------------
__global__ __launch_bounds__(256) void cvt3_f32_bf16(
    const float* __restrict__ s0, unsigned short* __restrict__ d0, int n0,
    const float* __restrict__ s1, unsigned short* __restrict__ d1, int n1,
    const float* __restrict__ s2, unsigned short* __restrict__ d2, int n2) {
    int i = blockIdx.x * 256 + threadIdx.x;
    const float* s; unsigned short* d;
    if (i < n0)           { s = s0; d = d0; }
    else if (i < n0 + n1) { i -= n0; s = s1; d = d1; }
    else                  { i -= n0 + n1; s = s2; d = d2; if (i >= n2) return; }
    const float4* sp = reinterpret_cast<const float4*>(s) + (size_t)i * 2;
    float4 a = sp[0], b = sp[1];
    ushort8v r;
    r[0] = f2b(a.x); r[1] = f2b(a.y); r[2] = f2b(a.z); r[3] = f2b(a.w);
    r[4] = f2b(b.x); r[5] = f2b(b.y); r[6] = f2b(b.z); r[7] = f2b(b.w);
    *(reinterpret_cast<ushort8v*>(d) + i) = r;
}

// ---------------------------------------------------------------------------
// QKV GEMM, split-K=2, XCD-affine 1D grid (1536 blocks).
// xcd=b&7 owns N-tiles [xcd*6, xcd*6+6) (B slice ~1.5MB/half, L2-resident);
// half = (b>=768) so K-halves are temporally separated; within a half the
// A-tile (bm) is reused by 6 consecutive blocks.
// 128x128 tile, BK=64. LDS addr(r,c8) = (r>>3)*1024B + c8*128B + (r&7)*16B.
// ---------------------------------------------------------------------------
__global__ __launch_bounds__(256) void gemm_qkv_splitk(
    const unsigned short* __restrict__ A, const unsigned short* __restrict__ B,
    const float* __restrict__ bias, unsigned short* __restrict__ P0,
    unsigned short* __restrict__ P1, int M, int N, int K) {
    __shared__ unsigned short As[128 * 64];
    __shared__ unsigned short Bs[128 * 64];
    const int tid = threadIdx.x;
    const int wave = tid >> 6, lane = tid & 63;
    const int row16 = lane & 15, quad = lane >> 4;
    const int wm = (wave >> 1) * 64, wn = (wave & 1) * 64;
    const int b = blockIdx.x;
    const int xcd = b & 7;
    int u = b >> 3;                        // [0,192)
    const int half = (u >= 96) ? 1 : 0;
    u -= half * 96;                        // [0,96)
    const int bn0 = (xcd * 6 + (u % 6)) * 128;
    const int bm0 = (u / 6) * 128;
    const int rl = lane & 7, cl = lane >> 3;
    const int kbeg = half * (K >> 1), kend = kbeg + (K >> 1);

    floatx4 acc[4][4] = {};

    for (int k0 = kbeg; k0 < kend; k0 += 64) {
        __syncthreads();                       // prev iter's frag reads done
        #pragma unroll
        for (int j = 0; j < 4; ++j) {
            int unit = wave * 4 + j;           // 8 tile-rows per unit
            const unsigned short* ga = A + (size_t)(bm0 + unit * 8 + rl) * K + k0 + cl * 8;
            gl2lds16(ga, &As[unit * 512 + lane * 8]);
            const unsigned short* gb = B + (size_t)(bn0 + unit * 8 + rl) * K + k0 + cl * 8;
            gl2lds16(gb, &Bs[unit * 512 + lane * 8]);
        }
        __syncthreads();                       // drains vmcnt -> data landed

        #pragma unroll
        for (int ks = 0; ks < 2; ++ks) {
            bf16x8 af[4], bfr[4];
            #pragma unroll
            for (int mt = 0; mt < 4; ++mt) {
                int r = wm + mt * 16 + row16;
                af[mt] = *reinterpret_cast<const bf16x8*>(
                    &As[(r >> 3) * 512 + (ks * 4 + quad) * 64 + (r & 7) * 8]);
            }
            #pragma unroll
            for (int nt = 0; nt < 4; ++nt) {
                int r = wn + nt * 16 + row16;
                bfr[nt] = *reinterpret_cast<const bf16x8*>(
                    &Bs[(r >> 3) * 512 + (ks * 4 + quad) * 64 + (r & 7) * 8]);
            }
            #pragma unroll
            for (int mt = 0; mt < 4; ++mt)
                #pragma unroll
                for (int nt = 0; nt < 4; ++nt)
                    acc[mt][nt] = mfma16(af[mt], bfr[nt], acc[mt][nt]);
        }
    }

    unsigned short* Cout = half ? P1 : P0;
    #pragma unroll
    for (int mt = 0; mt < 4; ++mt) {
        #pragma unroll
        for (int nt = 0; nt < 4; ++nt) {
            int gc = bn0 + wn + nt * 16 + row16;
            float bv = half ? 0.0f : bias[gc];
            int gr0 = bm0 + wm + mt * 16 + quad * 4;
            #pragma unroll
            for (int i = 0; i < 4; ++i)
                Cout[(size_t)(gr0 + i) * N + gc] = f2b(acc[mt][nt][i] + bv);
        }
    }
}

// ---------------------------------------------------------------------------
// out GEMM: C[2048,2048] = A @ B^T + bias, f32 out. 64x64 tile, XCD-affine
// 1D grid (1024 blocks): xcd=b&7 owns N-tiles [xcd*4, xcd*4+4).
// ---------------------------------------------------------------------------
__global__ __launch_bounds__(256) void gemm_out(
    const unsigned short* __restrict__ A, const unsigned short* __restrict__ B,
    const float* __restrict__ bias, float* __restrict__ Cout,
    int M, int N, int K) {
    __shared__ unsigned short As[64 * 64];
    __shared__ unsigned short Bs[64 * 64];
    const int tid = threadIdx.x;
    const int wave = tid >> 6, lane = tid & 63;
    const int row16 = lane & 15, quad = lane >> 4;
    const int wm = (wave >> 1) * 32, wn = (wave & 1) * 32;
    const int b = blockIdx.x;
    const int xcd = b & 7;
    const int u = b >> 3;                  // [0,128)
    const int bn0 = (xcd * 4 + (u & 3)) * 64;
    const int bm0 = (u >> 2) * 64;
    const int rl = lane & 7, cl = lane >> 3;

    floatx4 acc[2][2] = {};

    for (int k0 = 0; k0 < K; k0 += 64) {
        __syncthreads();
        #pragma unroll
        for (int j = 0; j < 2; ++j) {
            int unit = wave * 2 + j;
            const unsigned short* ga = A + (size_t)(bm0 + unit * 8 + rl) * K + k0 + cl * 8;
            gl2lds16(ga, &As[unit * 512 + lane * 8]);
            const unsigned short* gb = B + (size_t)(bn0 + unit * 8 + rl) * K + k0 + cl * 8;
            gl2lds16(gb, &Bs[unit * 512 + lane * 8]);
        }
        __syncthreads();

        #pragma unroll
        for (int ks = 0; ks < 2; ++ks) {
            bf16x8 af[2], bfr[2];
            #pragma unroll
            for (int mt = 0; mt < 2; ++mt) {
                int r = wm + mt * 16 + row16;
                af[mt] = *reinterpret_cast<const bf16x8*>(
                    &As[(r >> 3) * 512 + (ks * 4 + quad) * 64 + (r & 7) * 8]);
            }
            #pragma unroll
            for (int nt = 0; nt < 2; ++nt) {
                int r = wn + nt * 16 + row16;
                bfr[nt] = *reinterpret_cast<const bf16x8*>(
                    &Bs[(r >> 3) * 512 + (ks * 4 + quad) * 64 + (r & 7) * 8]);
            }
            #pragma unroll
            for (int mt = 0; mt < 2; ++mt)
                #pragma unroll
                for (int nt = 0; nt < 2; ++nt)
                    acc[mt][nt] = mfma16(af[mt], bfr[nt], acc[mt][nt]);
        }
    }

    #pragma unroll
    for (int mt = 0; mt < 2; ++mt) {
        #pragma unroll
        for (int nt = 0; nt < 2; ++nt) {
            int gc = bn0 + wn + nt * 16 + row16;
            float bv = bias[gc];
            int gr0 = bm0 + wm + mt * 16 + quad * 4;
            #pragma unroll
            for (int i = 0; i < 4; ++i)
                Cout[(size_t)(gr0 + i) * N + gc] = acc[mt][nt][i] + bv;
        }
    }
}

// ---------------------------------------------------------------------------
// tok GEMM split-K: C[2048,64] += gelu(P0+P1) @ [Bq;Bv]^T; C pre-zeroed.
// ---------------------------------------------------------------------------
template <int KSPLIT>
__global__ __launch_bounds__(256) void tok_gemm_splitk(
    const unsigned short* __restrict__ A0, const unsigned short* __restrict__ A1,
    const float* __restrict__ Bq, const float* __restrict__ Bv,
    float* __restrict__ C, int K) {
    constexpr int LDT = 72;
    __shared__ unsigned short As[64 * LDT];
    __shared__ unsigned short Bs[64 * LDT];
    const int tid = threadIdx.x;
    const int wave = tid >> 6, lane = tid & 63;
    const int row16 = lane & 15, quad = lane >> 4;
    const int wm = (wave >> 1) * 32, wn = (wave & 1) * 32;
    const int bm0 = blockIdx.y * 64;
    const int kbeg = blockIdx.x * KSPLIT;

    floatx4 acc[2][2] = {};

    for (int k0 = kbeg; k0 < kbeg + KSPLIT; k0 += 64) {
        #pragma unroll
        for (int it = 0; it < 2; ++it) {
            int i = tid + it * 256;
            int r = i >> 3, c8 = i & 7;
            size_t off = (size_t)(bm0 + r) * K + k0 + c8 * 8;
            ushort8v a0 = *reinterpret_cast<const ushort8v*>(A0 + off);
            ushort8v a1 = *reinterpret_cast<const ushort8v*>(A1 + off);
            ushort8v g;
            #pragma unroll
            for (int j = 0; j < 8; ++j) g[j] = f2b(gelu_f(b2f(a0[j]) + b2f(a1[j])));
            *reinterpret_cast<ushort8v*>(&As[r * LDT + c8 * 8]) = g;

            const float* brow = (r < 32) ? (Bq + (size_t)r * K) : (Bv + (size_t)(r - 32) * K);
            float4 w0 = *reinterpret_cast<const float4*>(brow + k0 + c8 * 8);
            float4 w1 = *reinterpret_cast<const float4*>(brow + k0 + c8 * 8 + 4);
            ushort8v wb;
            wb[0] = f2b(w0.x); wb[1] = f2b(w0.y); wb[2] = f2b(w0.z); wb[3] = f2b(w0.w);
            wb[4] = f2b(w1.x); wb[5] = f2b(w1.y); wb[6] = f2b(w1.z); wb[7] = f2b(w1.w);
            *reinterpret_cast<ushort8v*>(&Bs[r * LDT + c8 * 8]) = wb;
        }
        __syncthreads();

        #pragma unroll
        for (int ks = 0; ks < 2; ++ks) {
            bf16x8 af[2], bfr[2];
            #pragma unroll
            for (int mt = 0; mt < 2; ++mt)
                af[mt] = *reinterpret_cast<const bf16x8*>(
                    &As[(wm + mt * 16 + row16) * LDT + ks * 32 + quad * 8]);
            #pragma unroll
            for (int nt = 0; nt < 2; ++nt)
                bfr[nt] = *reinterpret_cast<const bf16x8*>(
                    &Bs[(wn + nt * 16 + row16) * LDT + ks * 32 + quad * 8]);
            #pragma unroll
            for (int mt = 0; mt < 2; ++mt)
                #pragma unroll
                for (int nt = 0; nt < 2; ++nt)
                    acc[mt][nt] = mfma16(af[mt], bfr[nt], acc[mt][nt]);
        }
        __syncthreads();
    }

    #pragma unroll
    for (int mt = 0; mt < 2; ++mt)
        #pragma unroll
        for (int nt = 0; nt < 2; ++nt) {
            int gc = wn + nt * 16 + row16;
            int gr0 = bm0 + wm + mt * 16 + quad * 4;
            #pragma unroll
            for (int i = 0; i < 4; ++i)
                atomicAdd(&C[(size_t)(gr0 + i) * 64 + gc], acc[mt][nt][i]);
        }
}

// ---------------------------------------------------------------------------
// tau gating + RoPE + layout transforms; qkv = P0+P1 (bf16 halves).
// Vectorized: each thread handles one (token, 8-wide d-chunk); RoPE partner
// chunk is c8^2. q pre-scaled by 0.125*log2e (for exp2 softmax).
// ---------------------------------------------------------------------------
__global__ __launch_bounds__(256) void qkv_process(
    const unsigned short* __restrict__ P0, const unsigned short* __restrict__ P1,
    const float* __restrict__ tok_raw, const float* __restrict__ tau_alpha,
    const int* __restrict__ positions, unsigned short* __restrict__ qh,
    unsigned short* __restrict__ kh, unsigned short* __restrict__ vtb) {
    const int h = blockIdx.y;
    const int t0 = blockIdx.x * 64;
    const int tid = threadIdx.x;
    __shared__ float vtr[64][65];
    __shared__ float tauq_s[64], tauv_s[64];

    if (tid < 64) {
        int t = t0 + tid;
        float pos = (float)positions[t];
        float pl = logf(fmaxf(pos + 1.0f, 1e-6f));
        float a = tau_alpha[h];
        float tp = 0.5f + 1.0f / (1.0f + __expf(-a * pl));
        tauq_s[tid] = tanhf(tok_raw[t * 64 + h]) + tp;
        tauv_s[tid] = tanhf(tok_raw[t * 64 + 32 + h]) + tp;
    }
    __syncthreads();

    const float QSCALE = 0.18033688011112042f;   // 0.125 * log2(e)
    #pragma unroll
    for (int it = 0; it < 2; ++it) {
        int idx = tid + it * 256;
        int tl = idx >> 3, c8 = idx & 7;
        int t = t0 + tl;
        size_t rb = (size_t)t * 6144 + h * 64 + c8 * 8;
        ushort8v q0v = *reinterpret_cast<const ushort8v*>(P0 + rb);
        ushort8v q1v = *reinterpret_cast<const ushort8v*>(P1 + rb);
        ushort8v k0v = *reinterpret_cast<const ushort8v*>(P0 + rb + 2048);
        ushort8v k1v = *reinterpret_cast<const ushort8v*>(P1 + rb + 2048);
        ushort8v v0v = *reinterpret_cast<const ushort8v*>(P0 + rb + 4096);
        ushort8v v1v = *reinterpret_cast<const ushort8v*>(P1 + rb + 4096);
        float tq = tauq_s[tl], tv = tauv_s[tl];
        float qo[8], ko[8];
        #pragma unroll
        for (int j = 0; j < 8; ++j) {
            qo[j] = (b2f(q0v[j]) + b2f(q1v[j])) * tq;
            ko[j] = b2f(k0v[j]) + b2f(k1v[j]);
        }
        if (c8 < 4) {                          // rotary chunks 0..3
            size_t rp = (size_t)t * 6144 + h * 64 + (c8 ^ 2) * 8;
            ushort8v qp0 = *reinterpret_cast<const ushort8v*>(P0 + rp);
            ushort8v qp1 = *reinterpret_cast<const ushort8v*>(P1 + rp);
            ushort8v kp0 = *reinterpret_cast<const ushort8v*>(P0 + rp + 2048);
            ushort8v kp1 = *reinterpret_cast<const ushort8v*>(P1 + rp + 2048);
            float pos = (float)positions[t];
            float sgn = (c8 < 2) ? -1.0f : 1.0f;
            #pragma unroll
            for (int j = 0; j < 8; ++j) {
                int fi = (c8 * 8 + j) & 15;
                float ang = pos * INV_FREQ[fi];
                float s, c;
                sincosf(ang, &s, &c);
                float qp = (b2f(qp0[j]) + b2f(qp1[j])) * tq;
                float kp = b2f(kp0[j]) + b2f(kp1[j]);
                qo[j] = qo[j] * c + sgn * qp * s;
                ko[j] = ko[j] * c + sgn * kp * s;
            }
        }
        size_t ob = ((size_t)h * 2048 + t) * 64 + c8 * 8;
        ushort8v qw, kw;
        #pragma unroll
        for (int j = 0; j < 8; ++j) {
            qw[j] = f2b(qo[j] * QSCALE);
            kw[j] = f2b(ko[j]);
        }
        *reinterpret_cast<ushort8v*>(qh + ob) = qw;
        *reinterpret_cast<ushort8v*>(kh + ob) = kw;
        #pragma unroll
        for (int j = 0; j < 8; ++j)
            vtr[c8 * 8 + j][tl] = (b2f(v0v[j]) + b2f(v1v[j])) * tv;
    }
    __syncthreads();
    #pragma unroll
    for (int it = 0; it < 2; ++it) {
        int idx = tid + it * 256;
        int d = idx >> 3, tc = (idx & 7) * 8;
        ushort8v w;
        #pragma unroll
        for (int j = 0; j < 8; ++j) w[j] = f2b(vtr[d][tc + j]);
        *reinterpret_cast<ushort8v*>(vtb + ((size_t)h * 64 + d) * 2048 + t0 + tc) = w;
    }
}

// ---------------------------------------------------------------------------
// s-split MAX-FREE flash attention, 64-q-row chunks, XCD-affine 1D schedule.
// 2560 blocks: b&7=XCD (4 heads/XCD), cpos=b>>5 walks 80 chunks longest-first.
// Wave w owns 16 q-rows (one m-frag) -> ~80 VGPR -> 6 blocks/CU.
// P = 2^s directly (scale folded into qh); masked -> 0.
// ---------------------------------------------------------------------------
__global__ __launch_bounds__(256, 6) void attn_fa(
    const unsigned short* __restrict__ qh, const unsigned short* __restrict__ kh,
    const unsigned short* __restrict__ vtb, unsigned short* __restrict__ Opart,
    float* __restrict__ ml) {
    constexpr int LD = 72;
    __shared__ unsigned short pbuf[4][16 * LD];      // [wave]
    const int b = blockIdx.x;
    const int h = (b & 7) + 8 * ((b >> 3) & 3);
    const int cpos = b >> 5;                         // [0,80)
    const int qt = CHUNK_QT[cpos], ch = CHUNK_C[cpos];
    const int q0 = qt * 64;
    const int slot = (h * 32 + qt) * 4 + ch;
    const int wave = threadIdx.x >> 6, lane = threadIdx.x & 63;
    const int m = lane & 15, quad = lane >> 4;
    const int qrow0 = q0 + wave * 16;
    const int sbeg = ch * 512;
    const int send = min(sbeg + 512, qrow0 + 16);

    const unsigned short* qptr = qh + ((size_t)h * 2048 + qrow0 + m) * 64;
    bf16x8 aq0 = *reinterpret_cast<const bf16x8*>(qptr + quad * 8);
    bf16x8 aq1 = *reinterpret_cast<const bf16x8*>(qptr + 32 + quad * 8);
    const unsigned short* kbase = kh + (size_t)h * 2048 * 64;
    const unsigned short* vbase = vtb + (size_t)h * 64 * 2048;

    floatx4 o[4] = {};
    float lsum[4] = {};

    for (int s0 = sbeg; s0 < send; s0 += 64) {
        floatx4 sc[4];
        #pragma unroll
        for (int sg = 0; sg < 4; ++sg) {
            const unsigned short* kr = kbase + (size_t)(s0 + sg * 16 + m) * 64;
            bf16x8 bk0 = *reinterpret_cast<const bf16x8*>(kr + quad * 8);
            bf16x8 bk1 = *reinterpret_cast<const bf16x8*>(kr + 32 + quad * 8);
            floatx4 z = {};
            z = mfma16(aq0, bk0, z);
            z = mfma16(aq1, bk1, z);
            sc[sg] = z;
        }
        if (s0 + 63 > qrow0) {               // only near-diagonal steps mask
            #pragma unroll
            for (int sg = 0; sg < 4; ++sg)
                #pragma unroll
                for (int i = 0; i < 4; ++i) {
                    int t = qrow0 + quad * 4 + i;
                    int s = s0 + sg * 16 + m;
                    sc[sg][i] = (s > t) ? -1e30f : sc[sg][i];
                }
        }
        // P = 2^s directly (max-free, scale pre-folded); masked -> 0
        #pragma unroll
        for (int sg = 0; sg < 4; ++sg)
            #pragma unroll
            for (int i = 0; i < 4; ++i)
                sc[sg][i] = fexp2(sc[sg][i]);
        #pragma unroll
        for (int i = 0; i < 4; ++i)
            lsum[i] += (sc[0][i] + sc[1][i]) + (sc[2][i] + sc[3][i]);

        // P: C-layout regs -> wave-private LDS -> A-layout frags (no barrier)
        unsigned short* pb = pbuf[wave];
        #pragma unroll
        for (int sg = 0; sg < 4; ++sg)
            #pragma unroll
            for (int i = 0; i < 4; ++i)
                pb[(quad * 4 + i) * LD + sg * 16 + m] = f2b_trunc(sc[sg][i]);
        bf16x8 ap0 = *reinterpret_cast<const bf16x8*>(&pb[m * LD + quad * 8]);
        bf16x8 ap1 = *reinterpret_cast<const bf16x8*>(&pb[m * LD + 32 + quad * 8]);
        #pragma unroll
        for (int nt = 0; nt < 4; ++nt) {
            const unsigned short* vr = vbase + (size_t)(nt * 16 + m) * 2048 + s0 + quad * 8;
            bf16x8 bv0 = *reinterpret_cast<const bf16x8*>(vr);
            bf16x8 bv1 = *reinterpret_cast<const bf16x8*>(vr + 32);
            o[nt] = mfma16(ap0, bv0, o[nt]);
            o[nt] = mfma16(ap1, bv1, o[nt]);
        }
    }

    // epilogue: reduce l across the 16 column-lanes, store partials
    #pragma unroll
    for (int d = 1; d < 16; d <<= 1)
        #pragma unroll
        for (int i = 0; i < 4; ++i)
            lsum[i] += __shfl_xor(lsum[i], d, 16);
    #pragma unroll
    for (int nt = 0; nt < 4; ++nt)
        #pragma unroll
        for (int i = 0; i < 4; ++i)
            Opart[((size_t)slot * 64 + wave * 16 + quad * 4 + i) * 64 + nt * 16 + m]
                = f2b(o[nt][i]);
    if (m == 0) {
        #pragma unroll
        for (int i = 0; i < 4; ++i)
            ml[(size_t)slot * 64 + wave * 16 + quad * 4 + i] = lsum[i];
    }
}

// ---------------------------------------------------------------------------
// Merge s-split partials (max-free): O = sum_c O~_c / sum_c l_c.
// Block = (qt in [0,32), h); thread t: row t/4, cols (t&3)*16 .. +16.
// ---------------------------------------------------------------------------
__global__ __launch_bounds__(256) void attn_merge(
    const unsigned short* __restrict__ Opart, const float* __restrict__ ml,
    unsigned short* __restrict__ attnb) {
    const int qt = blockIdx.x, h = blockIdx.y;
    const int nc = qt / 8 + 1;
    const int tid = threadIdx.x;
    const int r = tid >> 2, dh = (tid & 3) * 16;
    const int bs = (h * 32 + qt) * 4;

    float denom = 0.0f;
    #pragma unroll
    for (int c = 0; c < 4; ++c)
        if (c < nc) denom += ml[(size_t)(bs + c) * 64 + r];
    float inv = 1.0f / denom;

    float acc[16] = {};
    #pragma unroll
    for (int c = 0; c < 4; ++c) {
        if (c < nc) {
            const unsigned short* op = Opart + ((size_t)(bs + c) * 64 + r) * 64 + dh;
            #pragma unroll
            for (int j = 0; j < 2; ++j) {
                ushort8v v = *reinterpret_cast<const ushort8v*>(op + j * 8);
                #pragma unroll
                for (int k = 0; k < 8; ++k)
                    acc[j * 8 + k] += b2f(v[k]);
            }
        }
    }
    unsigned short* dst = attnb + (size_t)(qt * 64 + r) * 2048 + h * 64 + dh;
    #pragma unroll
    for (int j = 0; j < 2; ++j) {
        ushort8v v;
        #pragma unroll
        for (int k = 0; k < 8; ++k) v[k] = f2b(acc[j * 8 + k] * inv);
        *reinterpret_cast<ushort8v*>(dst + j * 8) = v;
    }
}

// ---------------------------------------------------------------------------
extern "C" void kernel_launch(void* const* d_in, const int* in_sizes, int n_in,
                              void* d_out, int out_size, void* d_ws, size_t ws_size,
                              hipStream_t stream) {
    const int*   positions = (const int*)d_in[0];
    const float* hidden    = (const float*)d_in[1];
    const float* Wqkv      = (const float*)d_in[2];
    const float* bqkv      = (const float*)d_in[3];
    const float* Wout      = (const float*)d_in[4];
    const float* bout      = (const float*)d_in[5];
    const float* tau_alpha = (const float*)d_in[6];
    const float* tau_wq    = (const float*)d_in[7];
    const float* tau_wv    = (const float*)d_in[8];

    unsigned char* ws = (unsigned char*)d_ws;
    unsigned short* P0      = (unsigned short*)(ws);             // 25165824
    unsigned short* P1      = (unsigned short*)(ws + 25165824);  // 25165824
    unsigned short* Opart   = (unsigned short*)(ws);             // reuses P0/P1
    unsigned short* wqb     = (unsigned short*)(ws + 50331648);  // dead after GEMM1
    unsigned short* qh      = (unsigned short*)(ws + 50331648);
    unsigned short* kh      = (unsigned short*)(ws + 58720256);
    unsigned short* vtb     = (unsigned short*)(ws + 67108864);
    unsigned short* hb      = (unsigned short*)(ws + 75497472);  // dead after GEMM1
    float*          tok_raw = (float*)(ws + 75497472);           // after hb dead
    unsigned short* attnb   = (unsigned short*)(ws + 75497472);  // after tok_raw dead
    float*          ml      = (float*)(ws + 83886080);
    unsigned short* wob     = (unsigned short*)(ws + 85983232);

    // 0) fp32 -> bf16 conversions (one launch, 3 segments)
    cvt3_f32_bf16<<<10240, 256, 0, stream>>>(
        hidden, hb, 524288, Wqkv, wqb, 1572864, Wout, wob, 524288);
    // 1) QKV GEMM split-K=2, XCD-affine (1536 blocks)
    gemm_qkv_splitk<<<1536, 256, 0, stream>>>(
        hb, wqb, bqkv, P0, P1, 2048, 6144, 2048);
    // 2) tok_raw = gelu(P0+P1) @ [tau_wq;tau_wv]^T  (split-K + atomics)
    hipMemsetAsync(tok_raw, 0, (size_t)2048 * 64 * 4, stream);
    tok_gemm_splitk<256><<<dim3(24, 32), 256, 0, stream>>>(
        P0, P1, tau_wq, tau_wv, tok_raw, 6144);
    // 3) gating + RoPE + layouts (vectorized; q scaled by 0.125*log2e)
    qkv_process<<<dim3(32, 32), 256, 0, stream>>>(
        P0, P1, tok_raw, tau_alpha, positions, qh, kh, vtb);
    // 4) s-split max-free flash attention, 64-row chunks, XCD-affine (2560)
    attn_fa<<<2560, 256, 0, stream>>>(qh, kh, vtb, Opart, ml);
    // 5) merge partials -> attnb
    attn_merge<<<dim3(32, 32), 256, 0, stream>>>(Opart, ml, attnb);
    // 6) out = attnb @ wob^T + bout  (64x64 tile, XCD-affine, 1024 blocks)
    gemm_out<<<1024, 256, 0, stream>>>(
        attnb, wob, bout, (float*)d_out, 2048, 2048, 2048);
}

// Round 11
// 414.576 us; speedup vs baseline: 1.1583x; 1.1583x over previous
//
#include <hip/hip_runtime.h>
#include <math.h>

// ---------------------------------------------------------------------------
// Moondream3Attention on MI355X (gfx950)
// T=2048, DIM=2048, H=32, HD=64, ROT=32, QKV_DIM=6144
// Pipeline (all-bf16 matmul datapath):  [R9 config + V fragment-packing]
//   0) cvt3: hidden->hb, Wqkv->wqb, Wout->wob (fp32->bf16, one launch)
//   1) qkv split-K=2: P0/P1 halves (128x128 tile, interleaved, 1536 blocks)
//   2) tok = gelu(P0+P1) @ [tau_wq;tau_wv]^T   (split-K + atomics)
//   3) qkv_process (ushort8-vectorized): P0+P1 sum, tau gating + RoPE;
//      V packed fragment-ordered: vpk[h][sb32][nt][quad][m][8] so attn's
//      B-frag load = base + lane*16B (fully coalesced, 1 txn vs 16)
//   4) attn_fa: s-split MAX-FREE flash attention, 128-q-row chunks,
//      2 m-frags/wave, XCD-affine (4 heads/XCD), 1280 blocks
//   5) attn_merge: O = sum_c O~_c / sum_c l_c -> attnb bf16
//   6) out = attnb @ wob^T + bout   (bf16 GEMM 64x64 tile, 1024 blocks)
// Workspace (94,371,840 B), liveness-overlapped:
//   P0    bf16 [2048][6144] @ 0          (25165824)  \ dead after qkv_process,
//   P1    bf16 [2048][6144] @ 25165824   (25165824)  / reused as Opart (33.5MB)
//   wqb   bf16 [6144][2048] @ 50331648   (25165824), dead after GEMM1 ->
//     qh  bf16 [32][2048][64] @ 50331648, kh @ 58720256, vpk @ 67108864
//   hb    bf16 [2048][2048] @ 75497472   (8388608), dead after GEMM1 ->
//     tok_raw f32 [2048][64] @ 75497472 (dead after qkv_process) ->
//     attnb   bf16 [2048][2048] @ 75497472
//   ml    f32 [2048][128]   @ 83886080  (1048576)
//   wob   bf16 [2048][2048] @ 85983232  (8388608)   -> end 94371840
// ---------------------------------------------------------------------------

typedef __bf16 bf16x8 __attribute__((ext_vector_type(8)));
typedef float floatx4 __attribute__((ext_vector_type(4)));
typedef unsigned short ushort8v __attribute__((ext_vector_type(8)));

__device__ __forceinline__ unsigned short f2b(float x) {
    unsigned int b = __float_as_uint(x);
    b = b + 0x7FFFu + ((b >> 16) & 1u);   // round-to-nearest-even
    return (unsigned short)(b >> 16);
}
__device__ __forceinline__ unsigned short f2b_trunc(float x) {
    return (unsigned short)(__float_as_uint(x) >> 16);   // cheap, for P only
}
__device__ __forceinline__ float b2f(unsigned short u) {
    return __uint_as_float(((unsigned int)u) << 16);
}
__device__ __forceinline__ float gelu_f(float x) {
    return 0.5f * x * (1.0f + erff(x * 0.70710678118654752440f));
}
__device__ __forceinline__ float fexp2(float x) {
    return __builtin_amdgcn_exp2f(x);     // raw v_exp_f32; x=-1e30 -> 0
}
__device__ __forceinline__ floatx4 mfma16(bf16x8 a, bf16x8 b, floatx4 c) {
    return __builtin_amdgcn_mfma_f32_16x16x32_bf16(a, b, c, 0, 0, 0);
}
// async global->LDS, 16B per lane; lane i lands at ldsbase + i*16
__device__ __forceinline__ void gl2lds16(const unsigned short* g, unsigned short* l) {
    __builtin_amdgcn_global_load_lds(
        (__attribute__((address_space(1))) void*)g,
        (__attribute__((address_space(3))) void*)l, 16, 0, 0);
}

// inv_freq[i] = 1e6^(-i/16), i = 0..15
__constant__ float INV_FREQ[16] = {
    1.0f, 0.42169650342858224f, 0.17782794100389228f, 0.074989420933245582f,
    0.031622776601683791f, 0.013335214321633240f, 0.0056234132519034908f,
    0.0023713737056616552f, 0.001f, 4.2169650342858224e-4f,
    1.7782794100389228e-4f, 7.4989420933245582e-5f, 3.1622776601683791e-5f,
    1.3335214321633240e-5f, 5.6234132519034908e-6f, 2.3713737056616552e-6f
};

// s-chunk schedule, 128-q-row tiles: nc = qt/4+1 chunks of 512 s (last partial).
// Ordered longest-first: 24 full (8-step) chunks, then 16 finals by length.
__constant__ unsigned char CHUNK_QT[40] = {
    15,15,15, 14,14,14, 13,13,13, 12,12,12, 11,11, 10,10, 9,9, 8,8, 7,6,5,4,
    15,11,7,3, 14,10,6,2, 13,9,5,1, 12,8,4,0};
__constant__ unsigned char CHUNK_C[40] = {
    0,1,2, 0,1,2, 0,1,2, 0,1,2, 0,1, 0,1, 0,1, 0,1, 0,0,0,0,
    3,2,1,0, 3,2,1,0, 3,2,1,0, 3,2,1,0};

// ---------------------------------------------------------------------------
// One-launch fp32->bf16 conversion of three buffers.
// ---------------------------------------------------------------------------
__global__ __launch_bounds__(256) void cvt3_f32_bf16(
    const float* __restrict__ s0, unsigned short* __restrict__ d0, int n0,
    const float* __restrict__ s1, unsigned short* __restrict__ d1, int n1,
    const float* __restrict__ s2, unsigned short* __restrict__ d2, int n2) {
    int i = blockIdx.x * 256 + threadIdx.x;
    const float* s; unsigned short* d;
    if (i < n0)           { s = s0; d = d0; }
    else if (i < n0 + n1) { i -= n0; s = s1; d = d1; }
    else                  { i -= n0 + n1; s = s2; d = d2; if (i >= n2) return; }
    const float4* sp = reinterpret_cast<const float4*>(s) + (size_t)i * 2;
    float4 a = sp[0], b = sp[1];
    ushort8v r;
    r[0] = f2b(a.x); r[1] = f2b(a.y); r[2] = f2b(a.z); r[3] = f2b(a.w);
    r[4] = f2b(b.x); r[5] = f2b(b.y); r[6] = f2b(b.z); r[7] = f2b(b.w);
    *(reinterpret_cast<ushort8v*>(d) + i) = r;
}

// ---------------------------------------------------------------------------
// QKV GEMM, split-K=2: 128x128 tile, BK=64. blockIdx.y bit0 selects K-half;
// half h computes over k in [h*K/2, (h+1)*K/2), writes bf16 partial to Ph.
// Bias folded into half 0. LDS addr(r,c8) = (r>>3)*1024B + c8*128B + (r&7)*16B.
// ---------------------------------------------------------------------------
__global__ __launch_bounds__(256) void gemm_qkv_splitk(
    const unsigned short* __restrict__ A, const unsigned short* __restrict__ B,
    const float* __restrict__ bias, unsigned short* __restrict__ P0,
    unsigned short* __restrict__ P1, int M, int N, int K) {
    __shared__ unsigned short As[128 * 64];
    __shared__ unsigned short Bs[128 * 64];
    const int tid = threadIdx.x;
    const int wave = tid >> 6, lane = tid & 63;
    const int row16 = lane & 15, quad = lane >> 4;
    const int wm = (wave >> 1) * 64, wn = (wave & 1) * 64;
    const int half = blockIdx.y & 1;
    const int bm0 = (blockIdx.y >> 1) * 128, bn0 = blockIdx.x * 128;
    const int rl = lane & 7, cl = lane >> 3;
    const int kbeg = half * (K >> 1), kend = kbeg + (K >> 1);

    floatx4 acc[4][4] = {};

    for (int k0 = kbeg; k0 < kend; k0 += 64) {
        __syncthreads();                       // prev iter's frag reads done
        #pragma unroll
        for (int j = 0; j < 4; ++j) {
            int unit = wave * 4 + j;           // 8 tile-rows per unit
            const unsigned short* ga = A + (size_t)(bm0 + unit * 8 + rl) * K + k0 + cl * 8;
            gl2lds16(ga, &As[unit * 512 + lane * 8]);
            const unsigned short* gb = B + (size_t)(bn0 + unit * 8 + rl) * K + k0 + cl * 8;
            gl2lds16(gb, &Bs[unit * 512 + lane * 8]);
        }
        __syncthreads();                       // drains vmcnt -> data landed

        #pragma unroll
        for (int ks = 0; ks < 2; ++ks) {
            bf16x8 af[4], bfr[4];
            #pragma unroll
            for (int mt = 0; mt < 4; ++mt) {
                int r = wm + mt * 16 + row16;
                af[mt] = *reinterpret_cast<const bf16x8*>(
                    &As[(r >> 3) * 512 + (ks * 4 + quad) * 64 + (r & 7) * 8]);
            }
            #pragma unroll
            for (int nt = 0; nt < 4; ++nt) {
                int r = wn + nt * 16 + row16;
                bfr[nt] = *reinterpret_cast<const bf16x8*>(
                    &Bs[(r >> 3) * 512 + (ks * 4 + quad) * 64 + (r & 7) * 8]);
            }
            #pragma unroll
            for (int mt = 0; mt < 4; ++mt)
                #pragma unroll
                for (int nt = 0; nt < 4; ++nt)
                    acc[mt][nt] = mfma16(af[mt], bfr[nt], acc[mt][nt]);
        }
    }

    unsigned short* Cout = half ? P1 : P0;
    #pragma unroll
    for (int mt = 0; mt < 4; ++mt) {
        #pragma unroll
        for (int nt = 0; nt < 4; ++nt) {
            int gc = bn0 + wn + nt * 16 + row16;
            float bv = half ? 0.0f : bias[gc];
            int gr0 = bm0 + wm + mt * 16 + quad * 4;
            #pragma unroll
            for (int i = 0; i < 4; ++i)
                Cout[(size_t)(gr0 + i) * N + gc] = f2b(acc[mt][nt][i] + bv);
        }
    }
}

// ---------------------------------------------------------------------------
// bf16 GEMM: C[M,N] = A[M,K] @ B[N,K]^T + bias[N].  BMxBN tile, BK=64.
// ---------------------------------------------------------------------------
template <int BM, int BN, bool OUT_BF16>
__global__ __launch_bounds__(256) void gemm_bf16_bt(
    const unsigned short* __restrict__ A, const unsigned short* __restrict__ B,
    const float* __restrict__ bias, void* __restrict__ Cout,
    int M, int N, int K) {
    constexpr int MT = BM / 32, NT = BN / 32;
    __shared__ unsigned short As[BM * 64];
    __shared__ unsigned short Bs[BN * 64];
    const int tid = threadIdx.x;
    const int wave = tid >> 6, lane = tid & 63;
    const int row16 = lane & 15, quad = lane >> 4;
    const int wm = (wave >> 1) * (BM / 2), wn = (wave & 1) * (BN / 2);
    const int bm0 = blockIdx.y * BM, bn0 = blockIdx.x * BN;
    const int rl = lane & 7, cl = lane >> 3;

    floatx4 acc[MT][NT] = {};

    for (int k0 = 0; k0 < K; k0 += 64) {
        __syncthreads();
        #pragma unroll
        for (int j = 0; j < BM / 32; ++j) {
            int unit = wave * (BM / 32) + j;
            const unsigned short* ga = A + (size_t)(bm0 + unit * 8 + rl) * K + k0 + cl * 8;
            gl2lds16(ga, &As[unit * 512 + lane * 8]);
        }
        #pragma unroll
        for (int j = 0; j < BN / 32; ++j) {
            int unit = wave * (BN / 32) + j;
            const unsigned short* gb = B + (size_t)(bn0 + unit * 8 + rl) * K + k0 + cl * 8;
            gl2lds16(gb, &Bs[unit * 512 + lane * 8]);
        }
        __syncthreads();

        #pragma unroll
        for (int ks = 0; ks < 2; ++ks) {
            bf16x8 af[MT], bfr[NT];
            #pragma unroll
            for (int mt = 0; mt < MT; ++mt) {
                int r = wm + mt * 16 + row16;
                af[mt] = *reinterpret_cast<const bf16x8*>(
                    &As[(r >> 3) * 512 + (ks * 4 + quad) * 64 + (r & 7) * 8]);
            }
            #pragma unroll
            for (int nt = 0; nt < NT; ++nt) {
                int r = wn + nt * 16 + row16;
                bfr[nt] = *reinterpret_cast<const bf16x8*>(
                    &Bs[(r >> 3) * 512 + (ks * 4 + quad) * 64 + (r & 7) * 8]);
            }
            #pragma unroll
            for (int mt = 0; mt < MT; ++mt)
                #pragma unroll
                for (int nt = 0; nt < NT; ++nt)
                    acc[mt][nt] = mfma16(af[mt], bfr[nt], acc[mt][nt]);
        }
    }

    #pragma unroll
    for (int mt = 0; mt < MT; ++mt) {
        #pragma unroll
        for (int nt = 0; nt < NT; ++nt) {
            int gc = bn0 + wn + nt * 16 + row16;
            float bv = bias[gc];
            int gr0 = bm0 + wm + mt * 16 + quad * 4;
            #pragma unroll
            for (int i = 0; i < 4; ++i) {
                float v = acc[mt][nt][i] + bv;
                if (OUT_BF16)
                    ((unsigned short*)Cout)[(size_t)(gr0 + i) * N + gc] = f2b(v);
                else
                    ((float*)Cout)[(size_t)(gr0 + i) * N + gc] = v;
            }
        }
    }
}

// ---------------------------------------------------------------------------
// tok GEMM split-K: C[2048,64] += gelu(P0+P1) @ [Bq;Bv]^T; C pre-zeroed.
// ---------------------------------------------------------------------------
template <int KSPLIT>
__global__ __launch_bounds__(256) void tok_gemm_splitk(
    const unsigned short* __restrict__ A0, const unsigned short* __restrict__ A1,
    const float* __restrict__ Bq, const float* __restrict__ Bv,
    float* __restrict__ C, int K) {
    constexpr int LDT = 72;
    __shared__ unsigned short As[64 * LDT];
    __shared__ unsigned short Bs[64 * LDT];
    const int tid = threadIdx.x;
    const int wave = tid >> 6, lane = tid & 63;
    const int row16 = lane & 15, quad = lane >> 4;
    const int wm = (wave >> 1) * 32, wn = (wave & 1) * 32;
    const int bm0 = blockIdx.y * 64;
    const int kbeg = blockIdx.x * KSPLIT;

    floatx4 acc[2][2] = {};

    for (int k0 = kbeg; k0 < kbeg + KSPLIT; k0 += 64) {
        #pragma unroll
        for (int it = 0; it < 2; ++it) {
            int i = tid + it * 256;
            int r = i >> 3, c8 = i & 7;
            size_t off = (size_t)(bm0 + r) * K + k0 + c8 * 8;
            ushort8v a0 = *reinterpret_cast<const ushort8v*>(A0 + off);
            ushort8v a1 = *reinterpret_cast<const ushort8v*>(A1 + off);
            ushort8v g;
            #pragma unroll
            for (int j = 0; j < 8; ++j) g[j] = f2b(gelu_f(b2f(a0[j]) + b2f(a1[j])));
            *reinterpret_cast<ushort8v*>(&As[r * LDT + c8 * 8]) = g;

            const float* brow = (r < 32) ? (Bq + (size_t)r * K) : (Bv + (size_t)(r - 32) * K);
            float4 w0 = *reinterpret_cast<const float4*>(brow + k0 + c8 * 8);
            float4 w1 = *reinterpret_cast<const float4*>(brow + k0 + c8 * 8 + 4);
            ushort8v wb;
            wb[0] = f2b(w0.x); wb[1] = f2b(w0.y); wb[2] = f2b(w0.z); wb[3] = f2b(w0.w);
            wb[4] = f2b(w1.x); wb[5] = f2b(w1.y); wb[6] = f2b(w1.z); wb[7] = f2b(w1.w);
            *reinterpret_cast<ushort8v*>(&Bs[r * LDT + c8 * 8]) = wb;
        }
        __syncthreads();

        #pragma unroll
        for (int ks = 0; ks < 2; ++ks) {
            bf16x8 af[2], bfr[2];
            #pragma unroll
            for (int mt = 0; mt < 2; ++mt)
                af[mt] = *reinterpret_cast<const bf16x8*>(
                    &As[(wm + mt * 16 + row16) * LDT + ks * 32 + quad * 8]);
            #pragma unroll
            for (int nt = 0; nt < 2; ++nt)
                bfr[nt] = *reinterpret_cast<const bf16x8*>(
                    &Bs[(wn + nt * 16 + row16) * LDT + ks * 32 + quad * 8]);
            #pragma unroll
            for (int mt = 0; mt < 2; ++mt)
                #pragma unroll
                for (int nt = 0; nt < 2; ++nt)
                    acc[mt][nt] = mfma16(af[mt], bfr[nt], acc[mt][nt]);
        }
        __syncthreads();
    }

    #pragma unroll
    for (int mt = 0; mt < 2; ++mt)
        #pragma unroll
        for (int nt = 0; nt < 2; ++nt) {
            int gc = wn + nt * 16 + row16;
            int gr0 = bm0 + wm + mt * 16 + quad * 4;
            #pragma unroll
            for (int i = 0; i < 4; ++i)
                atomicAdd(&C[(size_t)(gr0 + i) * 64 + gc], acc[mt][nt][i]);
        }
}

// ---------------------------------------------------------------------------
// tau gating + RoPE + layout transforms; qkv = P0+P1 (bf16 halves).
// V is packed fragment-ordered: vpk[h][sb32][nt][quad][m][8] where
// element = V[d=nt*16+m][s=sb*32+quad*8+j] -> attn B-frag load is
// base + lane*16B (fully coalesced). q pre-scaled by 0.125*log2e.
// ---------------------------------------------------------------------------
__global__ __launch_bounds__(256) void qkv_process(
    const unsigned short* __restrict__ P0, const unsigned short* __restrict__ P1,
    const float* __restrict__ tok_raw, const float* __restrict__ tau_alpha,
    const int* __restrict__ positions, unsigned short* __restrict__ qh,
    unsigned short* __restrict__ kh, unsigned short* __restrict__ vpk) {
    const int h = blockIdx.y;
    const int t0 = blockIdx.x * 64;
    const int tid = threadIdx.x;
    __shared__ float vtr[64][65];
    __shared__ float tauq_s[64], tauv_s[64];

    if (tid < 64) {
        int t = t0 + tid;
        float pos = (float)positions[t];
        float pl = logf(fmaxf(pos + 1.0f, 1e-6f));
        float a = tau_alpha[h];
        float tp = 0.5f + 1.0f / (1.0f + __expf(-a * pl));
        tauq_s[tid] = tanhf(tok_raw[t * 64 + h]) + tp;
        tauv_s[tid] = tanhf(tok_raw[t * 64 + 32 + h]) + tp;
    }
    __syncthreads();

    const float QSCALE = 0.18033688011112042f;   // 0.125 * log2(e)
    #pragma unroll
    for (int it = 0; it < 2; ++it) {
        int idx = tid + it * 256;
        int tl = idx >> 3, c8 = idx & 7;
        int t = t0 + tl;
        size_t rb = (size_t)t * 6144 + h * 64 + c8 * 8;
        ushort8v q0v = *reinterpret_cast<const ushort8v*>(P0 + rb);
        ushort8v q1v = *reinterpret_cast<const ushort8v*>(P1 + rb);
        ushort8v k0v = *reinterpret_cast<const ushort8v*>(P0 + rb + 2048);
        ushort8v k1v = *reinterpret_cast<const ushort8v*>(P1 + rb + 2048);
        ushort8v v0v = *reinterpret_cast<const ushort8v*>(P0 + rb + 4096);
        ushort8v v1v = *reinterpret_cast<const ushort8v*>(P1 + rb + 4096);
        float tq = tauq_s[tl], tv = tauv_s[tl];
        float qo[8], ko[8];
        #pragma unroll
        for (int j = 0; j < 8; ++j) {
            qo[j] = (b2f(q0v[j]) + b2f(q1v[j])) * tq;
            ko[j] = b2f(k0v[j]) + b2f(k1v[j]);
        }
        if (c8 < 4) {                          // rotary chunks 0..3
            size_t rp = (size_t)t * 6144 + h * 64 + (c8 ^ 2) * 8;
            ushort8v qp0 = *reinterpret_cast<const ushort8v*>(P0 + rp);
            ushort8v qp1 = *reinterpret_cast<const ushort8v*>(P1 + rp);
            ushort8v kp0 = *reinterpret_cast<const ushort8v*>(P0 + rp + 2048);
            ushort8v kp1 = *reinterpret_cast<const ushort8v*>(P1 + rp + 2048);
            float pos = (float)positions[t];
            float sgn = (c8 < 2) ? -1.0f : 1.0f;
            #pragma unroll
            for (int j = 0; j < 8; ++j) {
                int fi = (c8 * 8 + j) & 15;
                float ang = pos * INV_FREQ[fi];
                float s, c;
                sincosf(ang, &s, &c);
                float qp = (b2f(qp0[j]) + b2f(qp1[j])) * tq;
                float kp = b2f(kp0[j]) + b2f(kp1[j]);
                qo[j] = qo[j] * c + sgn * qp * s;
                ko[j] = ko[j] * c + sgn * kp * s;
            }
        }
        size_t ob = ((size_t)h * 2048 + t) * 64 + c8 * 8;
        ushort8v qw, kw;
        #pragma unroll
        for (int j = 0; j < 8; ++j) {
            qw[j] = f2b(qo[j] * QSCALE);
            kw[j] = f2b(ko[j]);
        }
        *reinterpret_cast<ushort8v*>(qh + ob) = qw;
        *reinterpret_cast<ushort8v*>(kh + ob) = kw;
        #pragma unroll
        for (int j = 0; j < 8; ++j)
            vtr[c8 * 8 + j][tl] = (b2f(v0v[j]) + b2f(v1v[j])) * tv;
    }
    __syncthreads();
    // V pack: vpk[h][sb32][nt][quad][m][8] = V[d=nt*16+m][s=sb*32+quad*8+j]
    #pragma unroll
    for (int it = 0; it < 2; ++it) {
        int idx = tid + it * 256;
        int d = idx >> 3, tc = (idx & 7) * 8;      // s-chunk [t0+tc, t0+tc+8)
        int sb = (t0 + tc) >> 5;
        int quad = (tc & 31) >> 3;
        int nt = d >> 4, m = d & 15;
        ushort8v w;
        #pragma unroll
        for (int j = 0; j < 8; ++j) w[j] = f2b(vtr[d][tc + j]);
        *reinterpret_cast<ushort8v*>(
            vpk + (size_t)h * 131072 + sb * 2048 + nt * 512 + quad * 128 + m * 8) = w;
    }
}

// ---------------------------------------------------------------------------
// s-split MAX-FREE flash attention, XCD-affine 1D schedule (R9 config).
// b&7 = XCD slot; head = (b&7) + 8*((b>>3)&3) -> 4 heads per XCD. cpos=b>>5
// walks 40 chunks longest-first. Wave owns 32 q-rows (2 m-frags).
// P = 2^s directly (scale folded into qh); masked -> 0.
// V loads from fragment-packed vpk: one coalesced 16B/lane load per frag.
// ---------------------------------------------------------------------------
__global__ __launch_bounds__(256) void attn_fa(
    const unsigned short* __restrict__ qh, const unsigned short* __restrict__ kh,
    const unsigned short* __restrict__ vpk, unsigned short* __restrict__ Opart,
    float* __restrict__ ml) {
    constexpr int LD = 72;
    __shared__ unsigned short pbuf[4][2][16 * LD];   // [wave][mt]
    const int b = blockIdx.x;
    const int h = (b & 7) + 8 * ((b >> 3) & 3);
    const int cpos = b >> 5;
    const int qt = CHUNK_QT[cpos], ch = CHUNK_C[cpos];
    const int q0 = qt * 128;
    const int slot = (h * 16 + qt) * 4 + ch;
    const int wave = threadIdx.x >> 6, lane = threadIdx.x & 63;
    const int m = lane & 15, quad = lane >> 4;
    const int qrow0 = q0 + wave * 32;
    const int sbeg = ch * 512;
    const int send = min(sbeg + 512, qrow0 + 32);

    bf16x8 aq[2][2];
    #pragma unroll
    for (int mt = 0; mt < 2; ++mt) {
        const unsigned short* qptr = qh + ((size_t)h * 2048 + qrow0 + mt * 16 + m) * 64;
        aq[mt][0] = *reinterpret_cast<const bf16x8*>(qptr + quad * 8);
        aq[mt][1] = *reinterpret_cast<const bf16x8*>(qptr + 32 + quad * 8);
    }
    const unsigned short* kbase = kh + (size_t)h * 2048 * 64;
    const unsigned short* vbase = vpk + (size_t)h * 131072;

    floatx4 o[2][4] = {};
    float lsum[2][4] = {};

    for (int s0 = sbeg; s0 < send; s0 += 64) {
        floatx4 sc[2][4];
        #pragma unroll
        for (int sg = 0; sg < 4; ++sg) {
            const unsigned short* kr = kbase + (size_t)(s0 + sg * 16 + m) * 64;
            bf16x8 bk0 = *reinterpret_cast<const bf16x8*>(kr + quad * 8);
            bf16x8 bk1 = *reinterpret_cast<const bf16x8*>(kr + 32 + quad * 8);
            #pragma unroll
            for (int mt = 0; mt < 2; ++mt) {
                floatx4 z = {};
                z = mfma16(aq[mt][0], bk0, z);
                z = mfma16(aq[mt][1], bk1, z);
                sc[mt][sg] = z;
            }
        }
        if (s0 + 63 > qrow0) {               // only near-diagonal steps mask
            #pragma unroll
            for (int mt = 0; mt < 2; ++mt)
                #pragma unroll
                for (int sg = 0; sg < 4; ++sg)
                    #pragma unroll
                    for (int i = 0; i < 4; ++i) {
                        int t = qrow0 + mt * 16 + quad * 4 + i;
                        int s = s0 + sg * 16 + m;
                        sc[mt][sg][i] = (s > t) ? -1e30f : sc[mt][sg][i];
                    }
        }
        // P = 2^s directly (max-free, scale pre-folded); masked -> 0
        #pragma unroll
        for (int mt = 0; mt < 2; ++mt)
            #pragma unroll
            for (int sg = 0; sg < 4; ++sg)
                #pragma unroll
                for (int i = 0; i < 4; ++i)
                    sc[mt][sg][i] = fexp2(sc[mt][sg][i]);
        #pragma unroll
        for (int mt = 0; mt < 2; ++mt)
            #pragma unroll
            for (int i = 0; i < 4; ++i)
                lsum[mt][i] += (sc[mt][0][i] + sc[mt][1][i]) + (sc[mt][2][i] + sc[mt][3][i]);

        // P: C-layout regs -> wave-private LDS -> A-layout frags (no barrier)
        unsigned short* pb0 = pbuf[wave][0];
        unsigned short* pb1 = pbuf[wave][1];
        #pragma unroll
        for (int sg = 0; sg < 4; ++sg)
            #pragma unroll
            for (int i = 0; i < 4; ++i) {
                pb0[(quad * 4 + i) * LD + sg * 16 + m] = f2b_trunc(sc[0][sg][i]);
                pb1[(quad * 4 + i) * LD + sg * 16 + m] = f2b_trunc(sc[1][sg][i]);
            }
        bf16x8 ap[2][2];
        #pragma unroll
        for (int mt = 0; mt < 2; ++mt) {
            ap[mt][0] = *reinterpret_cast<const bf16x8*>(&pbuf[wave][mt][m * LD + quad * 8]);
            ap[mt][1] = *reinterpret_cast<const bf16x8*>(&pbuf[wave][mt][m * LD + 32 + quad * 8]);
        }
        #pragma unroll
        for (int c = 0; c < 2; ++c) {
            const unsigned short* vrow = vbase + ((s0 >> 5) + c) * 2048;
            #pragma unroll
            for (int nt = 0; nt < 4; ++nt) {
                bf16x8 bv = *reinterpret_cast<const bf16x8*>(vrow + nt * 512 + lane * 8);
                o[0][nt] = mfma16(ap[0][c], bv, o[0][nt]);
                o[1][nt] = mfma16(ap[1][c], bv, o[1][nt]);
            }
        }
    }

    // epilogue: reduce l across the 16 column-lanes, store partials
    #pragma unroll
    for (int d = 1; d < 16; d <<= 1)
        #pragma unroll
        for (int mt = 0; mt < 2; ++mt)
            #pragma unroll
            for (int i = 0; i < 4; ++i)
                lsum[mt][i] += __shfl_xor(lsum[mt][i], d, 16);
    #pragma unroll
    for (int mt = 0; mt < 2; ++mt) {
        #pragma unroll
        for (int nt = 0; nt < 4; ++nt)
            #pragma unroll
            for (int i = 0; i < 4; ++i)
                Opart[((size_t)slot * 128 + wave * 32 + mt * 16 + quad * 4 + i) * 64 + nt * 16 + m]
                    = f2b(o[mt][nt][i]);
        if (m == 0) {
            #pragma unroll
            for (int i = 0; i < 4; ++i)
                ml[(size_t)slot * 128 + wave * 32 + mt * 16 + quad * 4 + i] = lsum[mt][i];
        }
    }
}

// ---------------------------------------------------------------------------
// Merge s-split partials (max-free): O = sum_c O~_c / sum_c l_c.
// Block = (qt, h); thread t: row t/2, cols (t&1)*32 .. +32.
// ---------------------------------------------------------------------------
__global__ __launch_bounds__(256) void attn_merge(
    const unsigned short* __restrict__ Opart, const float* __restrict__ ml,
    unsigned short* __restrict__ attnb) {
    const int qt = blockIdx.x, h = blockIdx.y;
    const int nc = qt / 4 + 1;
    const int tid = threadIdx.x;
    const int r = tid >> 1, dh = (tid & 1) * 32;
    const int bs = (h * 16 + qt) * 4;

    float denom = 0.0f;
    #pragma unroll
    for (int c = 0; c < 4; ++c)
        if (c < nc) denom += ml[(size_t)(bs + c) * 128 + r];
    float inv = 1.0f / denom;

    float acc[32] = {};
    #pragma unroll
    for (int c = 0; c < 4; ++c) {
        if (c < nc) {
            const unsigned short* op = Opart + ((size_t)(bs + c) * 128 + r) * 64 + dh;
            #pragma unroll
            for (int j = 0; j < 4; ++j) {
                ushort8v v = *reinterpret_cast<const ushort8v*>(op + j * 8);
                #pragma unroll
                for (int k = 0; k < 8; ++k)
                    acc[j * 8 + k] += b2f(v[k]);
            }
        }
    }
    unsigned short* dst = attnb + (size_t)(qt * 128 + r) * 2048 + h * 64 + dh;
    #pragma unroll
    for (int j = 0; j < 4; ++j) {
        ushort8v v;
        #pragma unroll
        for (int k = 0; k < 8; ++k) v[k] = f2b(acc[j * 8 + k] * inv);
        *reinterpret_cast<ushort8v*>(dst + j * 8) = v;
    }
}

// ---------------------------------------------------------------------------
extern "C" void kernel_launch(void* const* d_in, const int* in_sizes, int n_in,
                              void* d_out, int out_size, void* d_ws, size_t ws_size,
                              hipStream_t stream) {
    const int*   positions = (const int*)d_in[0];
    const float* hidden    = (const float*)d_in[1];
    const float* Wqkv      = (const float*)d_in[2];
    const float* bqkv      = (const float*)d_in[3];
    const float* Wout      = (const float*)d_in[4];
    const float* bout      = (const float*)d_in[5];
    const float* tau_alpha = (const float*)d_in[6];
    const float* tau_wq    = (const float*)d_in[7];
    const float* tau_wv    = (const float*)d_in[8];

    unsigned char* ws = (unsigned char*)d_ws;
    unsigned short* P0      = (unsigned short*)(ws);             // 25165824
    unsigned short* P1      = (unsigned short*)(ws + 25165824);  // 25165824
    unsigned short* Opart   = (unsigned short*)(ws);             // reuses P0/P1
    unsigned short* wqb     = (unsigned short*)(ws + 50331648);  // dead after GEMM1
    unsigned short* qh      = (unsigned short*)(ws + 50331648);
    unsigned short* kh      = (unsigned short*)(ws + 58720256);
    unsigned short* vpk     = (unsigned short*)(ws + 67108864);
    unsigned short* hb      = (unsigned short*)(ws + 75497472);  // dead after GEMM1
    float*          tok_raw = (float*)(ws + 75497472);           // after hb dead
    unsigned short* attnb   = (unsigned short*)(ws + 75497472);  // after tok_raw dead
    float*          ml      = (float*)(ws + 83886080);
    unsigned short* wob     = (unsigned short*)(ws + 85983232);

    // 0) fp32 -> bf16 conversions (one launch, 3 segments)
    cvt3_f32_bf16<<<10240, 256, 0, stream>>>(
        hidden, hb, 524288, Wqkv, wqb, 1572864, Wout, wob, 524288);
    // 1) QKV GEMM split-K=2 (128x128 tile, halves interleaved, 1536 blocks)
    gemm_qkv_splitk<<<dim3(48, 32), 256, 0, stream>>>(
        hb, wqb, bqkv, P0, P1, 2048, 6144, 2048);
    // 2) tok_raw = gelu(P0+P1) @ [tau_wq;tau_wv]^T  (split-K + atomics)
    hipMemsetAsync(tok_raw, 0, (size_t)2048 * 64 * 4, stream);
    tok_gemm_splitk<256><<<dim3(24, 32), 256, 0, stream>>>(
        P0, P1, tau_wq, tau_wv, tok_raw, 6144);
    // 3) gating + RoPE + layouts (vectorized; V fragment-packed)
    qkv_process<<<dim3(32, 32), 256, 0, stream>>>(
        P0, P1, tok_raw, tau_alpha, positions, qh, kh, vpk);
    // 4) s-split max-free flash attention, XCD-affine (1280 blocks)
    attn_fa<<<1280, 256, 0, stream>>>(qh, kh, vpk, Opart, ml);
    // 5) merge partials -> attnb
    attn_merge<<<dim3(16, 32), 256, 0, stream>>>(Opart, ml, attnb);
    // 6) out = attnb @ wob^T + bout  (64x64 tile -> 1024 blocks, 4/CU)
    gemm_bf16_bt<64, 64, false><<<dim3(32, 32), 256, 0, stream>>>(
        attnb, wob, bout, d_out, 2048, 2048, 2048);
}